// Round 4
// baseline (459.955 us; speedup 1.0000x reference)
//
#include <hip/hip_runtime.h>
#include <hip/hip_bf16.h>
#include <cstdint>

#define NB   2
#define NC   256
#define NSP  32768     // D*H*W
#define NG   32
#define CPG  8         // NC/NG
#define NH   8
#define HDIM 32
#define O3   768
#define NCH  64        // k_kv spatial chunks
#define GN_EPS 1e-5f

typedef __attribute__((ext_vector_type(4))) float f32x4;
typedef __attribute__((ext_vector_type(8))) short short8;
typedef __attribute__((ext_vector_type(4))) short s16x4;

static __device__ __forceinline__ float bf2f(unsigned short u) {
    union { unsigned int i; float f; } v; v.i = ((unsigned int)u) << 16; return v.f;
}
static __device__ __forceinline__ unsigned short f2bf(float f) {
    union { float f; unsigned int i; } v; v.f = f;
    unsigned int lsb = (v.i >> 16) & 1u;
    return (unsigned short)((v.i + 0x7fffu + lsb) >> 16);
}
static __device__ __forceinline__ float elu1(float x) {
    return x > 0.f ? x + 1.f : __expf(x);
}
// async global->LDS, 16B per lane; LDS dest must be wave-uniform base (linear fill).
static __device__ __forceinline__ void gload16(const unsigned short* g, unsigned short* l) {
    __builtin_amdgcn_global_load_lds((const __attribute__((address_space(1))) void*)g,
                                     (__attribute__((address_space(3))) void*)l, 16, 0, 0);
}

// ---------------- weight fp32 -> bf16 ----------------
__global__ __launch_bounds__(256) void k_convw(const float* __restrict__ qkvw,
                                               const float* __restrict__ outw,
                                               unsigned short* __restrict__ w16,
                                               unsigned short* __restrict__ ow16) {
    int i = blockIdx.x * 256 + threadIdx.x;
    for (int idx = i; idx < O3 * NC; idx += gridDim.x * 256) w16[idx] = f2bf(qkvw[idx]);
    for (int idx = i; idx < NC * NC; idx += gridDim.x * 256) ow16[idx] = f2bf(outw[idx]);
}

// ---------------- per-(b,c) sum/sumsq, fp32 input ----------------
__global__ __launch_bounds__(256) void k_stat_f32(const float* __restrict__ x, float* __restrict__ part) {
    int bc = blockIdx.x;
    const float* p = x + (size_t)bc * NSP;
    int t = threadIdx.x;
    float s = 0.f, s2 = 0.f;
    for (int i = t * 4; i < NSP; i += 256 * 4) {
        float4 v = *reinterpret_cast<const float4*>(p + i);
        s  += v.x + v.y + v.z + v.w;
        s2 += v.x * v.x + v.y * v.y + v.z * v.z + v.w * v.w;
    }
    #pragma unroll
    for (int o = 32; o > 0; o >>= 1) { s += __shfl_down(s, o, 64); s2 += __shfl_down(s2, o, 64); }
    __shared__ float red[8];
    if ((t & 63) == 0) { red[(t >> 6) * 2] = s; red[(t >> 6) * 2 + 1] = s2; }
    __syncthreads();
    if (t == 0) {
        part[bc * 2]     = red[0] + red[2] + red[4] + red[6];
        part[bc * 2 + 1] = red[1] + red[3] + red[5] + red[7];
    }
}

// ---------------- finalize group stats: per (b,g) mu, rsig ----------------
__global__ __launch_bounds__(64) void k_gnfin(const float* __restrict__ part, float* __restrict__ stat) {
    int i = threadIdx.x;
    if (i < NB * NG) {
        int b = i / NG, g = i % NG;
        float s = 0.f, s2 = 0.f;
        #pragma unroll
        for (int cc = 0; cc < CPG; ++cc) {
            int bc = b * NC + g * CPG + cc;
            s += part[bc * 2]; s2 += part[bc * 2 + 1];
        }
        float cnt = (float)(CPG * NSP);
        float mu = s / cnt;
        float var = s2 / cnt - mu * mu;
        stat[i * 2] = mu;
        stat[i * 2 + 1] = rsqrtf(var + GN_EPS);
    }
}

// ---------------- fused gn1-apply + qkv GEMM + bias + elu, store q/k/v bf16 ----------------
// grid (NSP/64, NB), 256 threads (4 waves). Tile M=768 (3 mp passes of 256) x N=64.
// W staged async into LDS per 32-K slice (permuted-linear layout for conflict-free b128 reads).
__global__ __launch_bounds__(256, 3) void k_qkv(const float* __restrict__ x,
                                             const float* __restrict__ nw, const float* __restrict__ nb,
                                             const unsigned short* __restrict__ w16,
                                             const float* __restrict__ qkvb,
                                             const float* __restrict__ gn1,
                                             unsigned short* __restrict__ qb,
                                             unsigned short* __restrict__ kb,
                                             unsigned short* __restrict__ vb) {
    __shared__ unsigned short Ht[64][264];   // h transposed [n][c], 33.8 KB
    __shared__ unsigned short Wl[8192];      // W tile 256x32, 16 KB, layout: grp*512 + kslot*128 + row15*8
    int b = blockIdx.y;
    int n0 = blockIdx.x * 64;
    int t = threadIdx.x;

    {   // stage h = (x-mu)*rsig*nw + nb: coalesced dword x-loads, packed b64 LDS writes
        int n = t & 63, cq = t >> 6;
        const float* xcol = x + (size_t)b * NC * NSP + n0 + n;
        #pragma unroll 8
        for (int pass = 0; pass < 16; ++pass) {
            int c0 = pass * 16 + cq * 4;
            s16x4 pk;
            #pragma unroll
            for (int i = 0; i < 4; ++i) {
                int c = c0 + i;
                float xv = xcol[(size_t)c * NSP];
                int g = c >> 3;
                float mu = gn1[(b * NG + g) * 2], rs = gn1[(b * NG + g) * 2 + 1];
                float sc = rs * nw[c];
                float bi = nb[c] - mu * sc;
                pk[i] = (short)f2bf(xv * sc + bi);
            }
            *reinterpret_cast<s16x4*>(&Ht[n][c0]) = pk;
        }
    }
    // no barrier needed here: first kc-iteration barrier orders Ht writes before reads

    int w = t >> 6, l = t & 63, mr = l & 15, kg = l >> 4;
    int j15 = l & 15, j4 = l >> 4;
    for (int mp = 0; mp < 3; ++mp) {
        f32x4 acc[4][4];
        #pragma unroll
        for (int a = 0; a < 4; ++a)
            #pragma unroll
            for (int n2 = 0; n2 < 4; ++n2) acc[a][n2] = (f32x4){0.f, 0.f, 0.f, 0.f};
        for (int kc = 0; kc < 8; ++kc) {
            // async-stage W[mp*256 .. +256)[kc*32 .. +32): 16 wave-loads of 1KB, 4 per wave
            #pragma unroll
            for (int it = 0; it < 4; ++it) {
                int grp = w * 4 + it;
                const unsigned short* gp = w16 + (size_t)(mp * 256 + grp * 16 + j15) * NC + kc * 32 + j4 * 8;
                gload16(gp, &Wl[grp * 512]);
            }
            __syncthreads();     // drains vmcnt (gload) + lgkm (Ht writes on first iter)
            short8 af[4], bfr[4];
            #pragma unroll
            for (int mt = 0; mt < 4; ++mt)
                af[mt] = *reinterpret_cast<const short8*>(&Wl[(w * 4 + mt) * 512 + kg * 128 + mr * 8]);
            int k0 = kc * 32 + kg * 8;
            #pragma unroll
            for (int nt = 0; nt < 4; ++nt)
                bfr[nt] = *reinterpret_cast<const short8*>(&Ht[nt * 16 + mr][k0]);
            #pragma unroll
            for (int mt = 0; mt < 4; ++mt)
                #pragma unroll
                for (int nt = 0; nt < 4; ++nt)
                    acc[mt][nt] = __builtin_amdgcn_mfma_f32_16x16x32_bf16(af[mt], bfr[nt], acc[mt][nt], 0, 0, 0);
            __syncthreads();     // all reads done before next stage overwrites Wl
        }
        unsigned short* dst = (mp == 0) ? qb : (mp == 1) ? kb : vb;
        #pragma unroll
        for (int mt = 0; mt < 4; ++mt) {
            #pragma unroll
            for (int nt = 0; nt < 4; ++nt) {
                int n = n0 + nt * 16 + mr;
                #pragma unroll
                for (int r = 0; r < 4; ++r) {
                    int olocal = w * 64 + mt * 16 + kg * 4 + r;
                    float val = acc[mt][nt][r] + qkvb[mp * 256 + olocal];
                    if (mp < 2) val = elu1(val);
                    dst[((size_t)(b * NC + olocal)) * NSP + n] = f2bf(val);
                }
            }
        }
    }
}

// ---------------- KV partials via MFMA: KV[d][e] = sum_n k[d][n] v[e][n] ----------------
// grid (NCH, NH, NB), 256 threads (4 waves). Per block: 512 n, per wave 128 n.
__global__ __launch_bounds__(256) void k_kv(const unsigned short* __restrict__ kb,
                                            const unsigned short* __restrict__ vb,
                                            float* __restrict__ KVpart, float* __restrict__ Spart) {
    int ch = blockIdx.x, h = blockIdx.y, b = blockIdx.z;
    int t = threadIdx.x, w = t >> 6, l = t & 63;
    int d16 = l & 15, kg = l >> 4;
    size_t base = ((size_t)(b * NC + h * HDIM)) * NSP + ch * 512 + w * 128;
    const unsigned short* kp = kb + base;
    const unsigned short* vp = vb + base;

    f32x4 acc[2][2];
    #pragma unroll
    for (int a = 0; a < 2; ++a)
        #pragma unroll
        for (int c = 0; c < 2; ++c) acc[a][c] = (f32x4){0.f, 0.f, 0.f, 0.f};
    float s0 = 0.f, s1 = 0.f;
    #pragma unroll
    for (int step = 0; step < 4; ++step) {
        int nof = step * 32 + kg * 8;
        short8 ak0 = *reinterpret_cast<const short8*>(kp + (size_t)(d16) * NSP + nof);
        short8 ak1 = *reinterpret_cast<const short8*>(kp + (size_t)(16 + d16) * NSP + nof);
        short8 av0 = *reinterpret_cast<const short8*>(vp + (size_t)(d16) * NSP + nof);
        short8 av1 = *reinterpret_cast<const short8*>(vp + (size_t)(16 + d16) * NSP + nof);
        acc[0][0] = __builtin_amdgcn_mfma_f32_16x16x32_bf16(ak0, av0, acc[0][0], 0, 0, 0);
        acc[0][1] = __builtin_amdgcn_mfma_f32_16x16x32_bf16(ak0, av1, acc[0][1], 0, 0, 0);
        acc[1][0] = __builtin_amdgcn_mfma_f32_16x16x32_bf16(ak1, av0, acc[1][0], 0, 0, 0);
        acc[1][1] = __builtin_amdgcn_mfma_f32_16x16x32_bf16(ak1, av1, acc[1][1], 0, 0, 0);
        #pragma unroll
        for (int j = 0; j < 8; ++j) { s0 += bf2f((unsigned short)ak0[j]); s1 += bf2f((unsigned short)ak1[j]); }
    }
    s0 += __shfl_down(s0, 32, 64); s0 += __shfl_down(s0, 16, 64);
    s1 += __shfl_down(s1, 32, 64); s1 += __shfl_down(s1, 16, 64);

    __shared__ float red[4][1024];
    __shared__ float sred[4][32];
    #pragma unroll
    for (int et = 0; et < 2; ++et)
        #pragma unroll
        for (int nt = 0; nt < 2; ++nt)
            #pragma unroll
            for (int r = 0; r < 4; ++r) {
                int d = et * 16 + kg * 4 + r;
                int e = nt * 16 + d16;
                red[w][d * 32 + e] = acc[et][nt][r];
            }
    if (l < 16) { sred[w][l] = s0; sred[w][16 + l] = s1; }
    __syncthreads();
    int bh = b * NH + h;
    float* kvout = KVpart + ((size_t)bh * NCH + ch) * 1024;
    for (int i = t; i < 1024; i += 256) kvout[i] = red[0][i] + red[1][i] + red[2][i] + red[3][i];
    if (t < 32) Spart[(bh * NCH + ch) * 32 + t] = sred[0][t] + sred[1][t] + sred[2][t] + sred[3][t];
}

// ---------------- reduce partials, KV2bf[e][d] = bf16(KV[d][e]/max(S[d],1e-6)) ----------------
__global__ __launch_bounds__(256) void k_kvfin(const float* __restrict__ KVpart, const float* __restrict__ Spart,
                                               unsigned short* __restrict__ KV2bf) {
    int bh = blockIdx.x, t = threadIdx.x;
    __shared__ float Sl[32];
    __shared__ float kvred[1024];
    if (t < 32) {
        float s = 0.f;
        for (int ch = 0; ch < NCH; ++ch) s += Spart[(bh * NCH + ch) * 32 + t];
        Sl[t] = fmaxf(s, 1e-6f);
    }
    for (int i = t; i < 1024; i += 256) {
        float s = 0.f;
        #pragma unroll 8
        for (int ch = 0; ch < NCH; ++ch) s += KVpart[((size_t)bh * NCH + ch) * 1024 + i];
        kvred[i] = s;
    }
    __syncthreads();
    for (int i = t; i < 1024; i += 256) {
        int d = i >> 5, e = i & 31;
        KV2bf[bh * 1024 + e * 32 + d] = f2bf(kvred[d * 32 + e] / Sl[d]);
    }
}

// ---------------- fused attn (MFMA) + out GEMM + bias + y-stats, store y bf16 ----------------
// grid (NSP/64, NB), 256 threads (4 waves). Wave handles 2 heads for attn; out-GEMM 256x64.
__global__ __launch_bounds__(256, 3) void k_attn(const unsigned short* __restrict__ qb,
                                              const unsigned short* __restrict__ KV2bf,
                                              const unsigned short* __restrict__ ow16,
                                              const float* __restrict__ outb,
                                              unsigned short* __restrict__ yb,
                                              float* __restrict__ gn2part) {
    __shared__ unsigned short qT[64][264];   // q transposed [n][c]; reused in-place as attn [n][c]
    __shared__ unsigned short Wl[8192];      // out_w tile 256x32
    int b = blockIdx.y, n0 = blockIdx.x * 64, t = threadIdx.x;

    {   // stage q transposed: coalesced u16 loads, b64 LDS writes
        int n = t & 63, cq = t >> 6;
        const unsigned short* qcol = qb + (size_t)b * NC * NSP + n0 + n;
        #pragma unroll 8
        for (int pass = 0; pass < 16; ++pass) {
            int c0 = pass * 16 + cq * 4;
            s16x4 pk;
            #pragma unroll
            for (int i = 0; i < 4; ++i) pk[i] = (short)qcol[(size_t)(c0 + i) * NSP];
            *reinterpret_cast<s16x4*>(&qT[n][c0]) = pk;
        }
    }
    __syncthreads();
    int w = t >> 6, l = t & 63, mr = l & 15, kg = l >> 4;
    int j15 = l & 15, j4 = l >> 4;

    // attn: wave w handles heads 2w, 2w+1. D[e][n] = sum_d KV2[d][e] q[d][n], then /qsum.
    #pragma unroll
    for (int hh = 0; hh < 2; ++hh) {
        int h = w * 2 + hh;
        const unsigned short* kvp = KV2bf + (b * NH + h) * 1024;
        short8 a0 = *reinterpret_cast<const short8*>(kvp + mr * 32 + kg * 8);
        short8 a1 = *reinterpret_cast<const short8*>(kvp + (16 + mr) * 32 + kg * 8);
        short8 bfr[4];
        float qsum[4];
        #pragma unroll
        for (int nt = 0; nt < 4; ++nt) {
            bfr[nt] = *reinterpret_cast<const short8*>(&qT[nt * 16 + mr][h * HDIM + kg * 8]);
            float s = 0.f;
            #pragma unroll
            for (int j = 0; j < 8; ++j) s += bf2f((unsigned short)bfr[nt][j]);
            s += __shfl_xor(s, 16, 64);
            s += __shfl_xor(s, 32, 64);
            qsum[nt] = fmaxf(s, 1e-6f);
        }
        f32x4 acc[2][4];
        #pragma unroll
        for (int et = 0; et < 2; ++et)
            #pragma unroll
            for (int nt = 0; nt < 4; ++nt) acc[et][nt] = (f32x4){0.f, 0.f, 0.f, 0.f};
        #pragma unroll
        for (int nt = 0; nt < 4; ++nt) {
            acc[0][nt] = __builtin_amdgcn_mfma_f32_16x16x32_bf16(a0, bfr[nt], acc[0][nt], 0, 0, 0);
            acc[1][nt] = __builtin_amdgcn_mfma_f32_16x16x32_bf16(a1, bfr[nt], acc[1][nt], 0, 0, 0);
        }
        #pragma unroll
        for (int et = 0; et < 2; ++et)
            #pragma unroll
            for (int nt = 0; nt < 4; ++nt) {
                int n = nt * 16 + mr;
                float inv = 1.0f / qsum[nt];
                #pragma unroll
                for (int r = 0; r < 4; ++r)
                    qT[n][h * HDIM + et * 16 + kg * 4 + r] = f2bf(acc[et][nt][r] * inv);
            }
    }
    // out GEMM: y[o][n] = sum_c ow[o][c] * attn[c][n] + outb[o]
    f32x4 acc[4][4];
    #pragma unroll
    for (int a = 0; a < 4; ++a)
        #pragma unroll
        for (int n2 = 0; n2 < 4; ++n2) acc[a][n2] = (f32x4){0.f, 0.f, 0.f, 0.f};
    for (int kc = 0; kc < 8; ++kc) {
        #pragma unroll
        for (int it = 0; it < 4; ++it) {
            int grp = w * 4 + it;
            const unsigned short* gp = ow16 + (size_t)(grp * 16 + j15) * NC + kc * 32 + j4 * 8;
            gload16(gp, &Wl[grp * 512]);
        }
        __syncthreads();     // first iter also orders all waves' attn writebacks
        short8 af[4], bfr[4];
        #pragma unroll
        for (int mt = 0; mt < 4; ++mt)
            af[mt] = *reinterpret_cast<const short8*>(&Wl[(w * 4 + mt) * 512 + kg * 128 + mr * 8]);
        int k0 = kc * 32 + kg * 8;
        #pragma unroll
        for (int nt = 0; nt < 4; ++nt)
            bfr[nt] = *reinterpret_cast<const short8*>(&qT[nt * 16 + mr][k0]);
        #pragma unroll
        for (int mt = 0; mt < 4; ++mt)
            #pragma unroll
            for (int nt = 0; nt < 4; ++nt)
                acc[mt][nt] = __builtin_amdgcn_mfma_f32_16x16x32_bf16(af[mt], bfr[nt], acc[mt][nt], 0, 0, 0);
        __syncthreads();
    }
    // epilogue: store y, accumulate gn2 stats (sum, sumsq) per channel
    float s1[16], s2[16];
    #pragma unroll
    for (int i = 0; i < 16; ++i) { s1[i] = 0.f; s2[i] = 0.f; }
    #pragma unroll
    for (int mt = 0; mt < 4; ++mt) {
        #pragma unroll
        for (int nt = 0; nt < 4; ++nt) {
            int n = n0 + nt * 16 + mr;
            #pragma unroll
            for (int r = 0; r < 4; ++r) {
                int o = w * 64 + mt * 16 + kg * 4 + r;
                float val = acc[mt][nt][r] + outb[o];
                yb[((size_t)(b * NC + o)) * NSP + n] = f2bf(val);
                s1[mt * 4 + r] += val;
                s2[mt * 4 + r] += val * val;
            }
        }
    }
    #pragma unroll
    for (int i = 0; i < 16; ++i) {
        float a = s1[i], q2 = s2[i];
        a += __shfl_down(a, 8, 64);  q2 += __shfl_down(q2, 8, 64);
        a += __shfl_down(a, 4, 64);  q2 += __shfl_down(q2, 4, 64);
        a += __shfl_down(a, 2, 64);  q2 += __shfl_down(q2, 2, 64);
        a += __shfl_down(a, 1, 64);  q2 += __shfl_down(q2, 1, 64);
        if (mr == 0) {
            int o = w * 64 + (i >> 2) * 16 + kg * 4 + (i & 3);
            atomicAdd(&gn2part[(b * NC + o) * 2], a);
            atomicAdd(&gn2part[(b * NC + o) * 2 + 1], q2);
        }
    }
}

// ---------------- final: out = x + gn2(y) ----------------
__global__ __launch_bounds__(256) void k_final(const float* __restrict__ x,
                                               const unsigned short* __restrict__ yb,
                                               const float* __restrict__ onw, const float* __restrict__ onb,
                                               const float* __restrict__ gn2, float* __restrict__ out) {
    size_t base = ((size_t)blockIdx.x * 256 + threadIdx.x) * 8;
    int bc = (int)(base >> 15);           // b*NC + c
    int c = bc & (NC - 1);
    int b = bc >> 8;
    int g = c >> 3;
    float mu = gn2[(b * NG + g) * 2], rs = gn2[(b * NG + g) * 2 + 1];
    float sc = rs * onw[c], bi = onb[c] - mu * sc;
    short8 v = *reinterpret_cast<const short8*>(yb + base);
    float4 x0 = *reinterpret_cast<const float4*>(x + base);
    float4 x1 = *reinterpret_cast<const float4*>(x + base + 4);
    float4 o0, o1;
    o0.x = x0.x + bf2f((unsigned short)v[0]) * sc + bi;
    o0.y = x0.y + bf2f((unsigned short)v[1]) * sc + bi;
    o0.z = x0.z + bf2f((unsigned short)v[2]) * sc + bi;
    o0.w = x0.w + bf2f((unsigned short)v[3]) * sc + bi;
    o1.x = x1.x + bf2f((unsigned short)v[4]) * sc + bi;
    o1.y = x1.y + bf2f((unsigned short)v[5]) * sc + bi;
    o1.z = x1.z + bf2f((unsigned short)v[6]) * sc + bi;
    o1.w = x1.w + bf2f((unsigned short)v[7]) * sc + bi;
    *reinterpret_cast<float4*>(out + base) = o0;
    *reinterpret_cast<float4*>(out + base + 4) = o1;
}

extern "C" void kernel_launch(void* const* d_in, const int* in_sizes, int n_in,
                              void* d_out, int out_size, void* d_ws, size_t ws_size,
                              hipStream_t stream) {
    const float* x      = (const float*)d_in[0];
    const float* norm_w = (const float*)d_in[1];
    const float* norm_b = (const float*)d_in[2];
    const float* qkv_w  = (const float*)d_in[3];
    const float* qkv_b  = (const float*)d_in[4];
    const float* out_w  = (const float*)d_in[5];
    const float* out_b  = (const float*)d_in[6];
    const float* onw    = (const float*)d_in[7];
    const float* onb    = (const float*)d_in[8];
    float* out = (float*)d_out;

    char* w = (char*)d_ws;
    size_t off = 0;
    auto al = [&](size_t n) { size_t o = off; off += (n + 255) & ~(size_t)255; return o; };
    const size_t bufsz = (size_t)NB * NC * NSP * 2;          // 33.5 MB each
    unsigned short* qbuf = (unsigned short*)(w + al(bufsz));
    unsigned short* kbuf = (unsigned short*)(w + al(bufsz));
    unsigned short* vbuf = (unsigned short*)(w + al(bufsz));
    unsigned short* ybuf = (unsigned short*)(w + al(bufsz));
    unsigned short* w16  = (unsigned short*)(w + al((size_t)O3 * NC * 2));
    unsigned short* ow16 = (unsigned short*)(w + al((size_t)NC * NC * 2));
    float* gn1part = (float*)(w + al((size_t)NB * NC * 2 * 4));
    float* gn1stat = (float*)(w + al((size_t)NB * NG * 2 * 4));
    float* gn2part = (float*)(w + al((size_t)NB * NC * 2 * 4));
    float* gn2stat = (float*)(w + al((size_t)NB * NG * 2 * 4));
    unsigned short* KV2bf = (unsigned short*)(w + al((size_t)NB * NH * HDIM * HDIM * 2));
    // KVpart/Spart alias ybuf: fully consumed by k_kvfin before k_attn writes ybuf.
    float* KVpart = (float*)ybuf;                                        // 16*NCH*1024*4 = 4 MB
    float* Spart  = (float*)(ybuf + (size_t)NB * NH * NCH * 1024 * 2);   // after KVpart

    (void)hipMemsetAsync(gn2part, 0, (size_t)NB * NC * 2 * sizeof(float), stream);

    k_convw<<<dim3(256), dim3(256), 0, stream>>>(qkv_w, out_w, w16, ow16);
    k_stat_f32<<<dim3(NB * NC), dim3(256), 0, stream>>>(x, gn1part);
    k_gnfin<<<dim3(1), dim3(64), 0, stream>>>(gn1part, gn1stat);
    k_qkv<<<dim3(NSP / 64, NB), dim3(256), 0, stream>>>(x, norm_w, norm_b, w16, qkv_b, gn1stat,
                                                        qbuf, kbuf, vbuf);
    k_kv<<<dim3(NCH, NH, NB), dim3(256), 0, stream>>>(kbuf, vbuf, KVpart, Spart);
    k_kvfin<<<dim3(NB * NH), dim3(256), 0, stream>>>(KVpart, Spart, KV2bf);
    k_attn<<<dim3(NSP / 64, NB), dim3(256), 0, stream>>>(qbuf, KV2bf, ow16, out_b, ybuf, gn2part);
    k_gnfin<<<dim3(1), dim3(64), 0, stream>>>(gn2part, gn2stat);
    k_final<<<dim3((NB * NC * NSP) / (256 * 8)), dim3(256), 0, stream>>>(x, ybuf, onw, onb, gn2stat, out);
}